// Round 4
// baseline (311.972 us; speedup 1.0000x reference)
//
#include <hip/hip_runtime.h>
#include <hip/hip_bf16.h>

// Problem constants
#define NB 4
#define NT 4096
#define NE 1024
#define ND 128
// log2(e) / sqrt(128): folded into Wq at prep so attention uses exp2 directly.
#define QSCALE 0.12751741f

typedef unsigned u32x4 __attribute__((ext_vector_type(4)));
typedef float f32x4 __attribute__((ext_vector_type(4)));
typedef float f32x16 __attribute__((ext_vector_type(16)));
typedef __bf16 bf16x8 __attribute__((ext_vector_type(8)));
typedef unsigned short u16;

__device__ __forceinline__ unsigned cvt_pk_bf16(float lo, float hi) {
  unsigned r;
  asm("v_cvt_pk_bf16_f32 %0, %1, %2" : "=v"(r) : "v"(lo), "v"(hi));
  return r;
}
__device__ __forceinline__ void permswap(unsigned& a, unsigned& b) {
  asm("v_permlane32_swap_b32 %0, %1" : "+v"(a), "+v"(b));
}
__device__ __forceinline__ u16 f2bf(float f) {  // RNE f32->bf16
  unsigned x = __float_as_uint(f);
  x += 0x7fffu + ((x >> 16) & 1u);
  return (u16)(x >> 16);
}
__device__ __forceinline__ float bf2f(u16 u) {
  return __uint_as_float(((unsigned)u) << 16);
}
__device__ __forceinline__ f32x16 mfma32(bf16x8 a, bf16x8 b, f32x16 c) {
  return __builtin_amdgcn_mfma_f32_32x32x16_bf16(a, b, c, 0, 0, 0);
}
__device__ __forceinline__ bf16x8 ldb(const u16* p) {
  return *reinterpret_cast<const bf16x8*>(p);
}
// P(f32x16, C/D layout) -> two bf16x8 B-fragments for PV
__device__ __forceinline__ void pack_pf(const f32x16& pr, bf16x8& f0, bf16x8& f1) {
  unsigned pk[8];
#pragma unroll
  for (int i = 0; i < 8; ++i) pk[i] = cvt_pk_bf16(pr[2 * i], pr[2 * i + 1]);
  permswap(pk[0], pk[2]);
  permswap(pk[1], pk[3]);
  permswap(pk[4], pk[6]);
  permswap(pk[5], pk[7]);
  u32x4 t0, t1;
  t0[0] = pk[0]; t0[1] = pk[1]; t0[2] = pk[2]; t0[3] = pk[3];
  t1[0] = pk[4]; t1[1] = pk[5]; t1[2] = pk[6]; t1[3] = pk[7];
  f0 = __builtin_bit_cast(bf16x8, t0);
  f1 = __builtin_bit_cast(bf16x8, t1);
}

// ---------------- Kernel 0: W[e][d] -> WT bf16 [3][128 d][1024 e] ----------
__global__ void ah_prep(const float* __restrict__ Wq, const float* __restrict__ Wk,
                        const float* __restrict__ Wv, u16* __restrict__ wt) {
  const int m = blockIdx.x >> 5;
  const int r = blockIdx.x & 31;
  const int e0 = (r >> 1) * 64;
  const int d0 = (r & 1) * 64;
  const float* W = (m == 0) ? Wq : (m == 1) ? Wk : Wv;
  const float s = (m == 0) ? QSCALE : 1.0f;
  __shared__ u16 lds[64][68];             // [d][e]
  const int t = threadIdx.x;
  const int row = t >> 2;
  const int c0 = (t & 3) * 16;
  const float* src = W + (size_t)(e0 + row) * ND + d0 + c0;
#pragma unroll
  for (int i = 0; i < 16; i += 4) {
    f32x4 v = *reinterpret_cast<const f32x4*>(src + i);
#pragma unroll
    for (int j = 0; j < 4; ++j) lds[c0 + i + j][row] = f2bf(v[j] * s);
  }
  __syncthreads();
  const int d = t >> 2;
  const int ec = (t & 3) * 16;
  u16* dst = wt + (size_t)m * NE * ND + (size_t)(d0 + d) * NE + e0 + ec;
  u32x4 o0, o1;
#pragma unroll
  for (int j = 0; j < 4; ++j)
    o0[j] = (unsigned)lds[d][ec + 2 * j] | ((unsigned)lds[d][ec + 2 * j + 1] << 16);
#pragma unroll
  for (int j = 0; j < 4; ++j)
    o1[j] = (unsigned)lds[d][ec + 8 + 2 * j] | ((unsigned)lds[d][ec + 8 + 2 * j + 1] << 16);
  *reinterpret_cast<u32x4*>(dst) = o0;
  *reinterpret_cast<u32x4*>(dst + 8) = o1;
}

// ---------------- Kernel 1: fused QKV projection ---------------------------
// 512 blocks x 4 waves; block = 32 rows; wave w owns d-cols [w*32,w*32+32)
// of all three mats (X read once). Unroll 4 => 8 X-loads in flight per wave.
__global__ __launch_bounds__(256, 2) void ah_proj(
    const float* __restrict__ X, const u16* __restrict__ wt,
    u16* __restrict__ qb, u16* __restrict__ kb, u16* __restrict__ vtb) {
  const int row0 = blockIdx.x * 32;
  const int tid = threadIdx.x;
  const int w = tid >> 6;
  const int lane = tid & 63;
  const int l31 = lane & 31;
  const int h = lane >> 5;

  const float* xrow = X + (size_t)(row0 + l31) * NE + h * 8;
  const u16* wpQ = wt + (size_t)(w * 32 + l31) * NE + h * 8;
  const u16* wpK = wpQ + (size_t)NE * ND;
  const u16* wpV = wpK + (size_t)NE * ND;

  f32x16 accQ = {}, accK = {}, accV = {};

#pragma unroll 4
  for (int e0 = 0; e0 < NE; e0 += 16) {
    f32x4 x0 = *reinterpret_cast<const f32x4*>(xrow + e0);
    f32x4 x1 = *reinterpret_cast<const f32x4*>(xrow + e0 + 4);
    u32x4 xw;
    xw[0] = cvt_pk_bf16(x0[0], x0[1]);
    xw[1] = cvt_pk_bf16(x0[2], x0[3]);
    xw[2] = cvt_pk_bf16(x1[0], x1[1]);
    xw[3] = cvt_pk_bf16(x1[2], x1[3]);
    bf16x8 xf = __builtin_bit_cast(bf16x8, xw);
    accQ = mfma32(xf, ldb(wpQ + e0), accQ);   // D[t][d]
    accK = mfma32(xf, ldb(wpK + e0), accK);   // D[t][d]
    accV = mfma32(ldb(wpV + e0), xf, accV);   // D[d][t]  (V^T)
  }

  const int col = w * 32 + l31;
#pragma unroll
  for (int r = 0; r < 16; ++r) {
    const int trow = row0 + (r & 3) + 8 * (r >> 2) + 4 * h;
    qb[(size_t)trow * ND + col] = f2bf(accQ[r]);
    kb[(size_t)trow * ND + col] = f2bf(accK[r]);
  }
  const int bb = row0 >> 12;
  const int tt = (row0 & 4095) + l31;
#pragma unroll
  for (int r = 0; r < 16; ++r) {
    const int d = w * 32 + (r & 3) + 8 * (r >> 2) + 4 * h;
    vtb[(size_t)bb * ND * NT + (size_t)d * NT + tt] = f2bf(accV[r]);
  }
}

// ---------------- Kernel 2: split-K causal flash attention -----------------
// 1280 blocks x 4 waves. Unit = (b, qt, chunk of <=32 KV tiles). Per-XCD:
// 160 units (batch = xcd>>1, qt parity = xcd&1), ordered work-descending.
// Block writes UNNORMALIZED partial (m,l f32 + O^T-combined O[q][d] bf16).
__global__ __launch_bounds__(256, 4) void ah_attn_sk(
    const u16* __restrict__ qg, const u16* __restrict__ kg,
    const u16* __restrict__ vtg, u16* __restrict__ opart,
    float* __restrict__ ml) {
  __shared__ float smem_m[4][32];
  __shared__ float smem_l[4][32];
  __shared__ float smemO[128][33];

  const int bid = blockIdx.x;
  const int x = bid & 7;
  const int s = bid >> 3;                 // 0..159 per XCD
  const int b = x >> 1;
  const int p = x & 1;
  int r, c;
  if (s < 64)       { r = s >> 2;               c = s & 3; }
  else if (s < 112) { int t = s - 64; int q3 = t / 3; r = 16 + q3; c = t - 3 * q3; }
  else if (s < 144) { int t = s - 112; r = 32 + (t >> 1); c = t & 1; }
  else              { r = 48 + (s - 144);       c = 0; }
  const int qt = (126 + p) - 2 * r;
  const int q0 = qt * 32;
  const int jbeg = c * 32;
  const int jend = min(jbeg + 32, qt + 1);

  const int tid = threadIdx.x;
  const int w = tid >> 6;
  const int lane = tid & 63;
  const int l31 = lane & 31;
  const int h = lane >> 5;

  const u16* Qb = qg + (size_t)b * NT * ND;
  const u16* Kb = kg + (size_t)b * NT * ND;
  const u16* VTb = vtg + (size_t)b * ND * NT;

  bf16x8 qf[8];
  {
    const u16* qrow = Qb + (size_t)(q0 + l31) * ND + h * 8;
#pragma unroll
    for (int sI = 0; sI < 8; ++sI) qf[sI] = ldb(qrow + sI * 16);
  }

  float m_run = -1e30f, l_run = 0.f;
  f32x16 ot[4] = {};

  for (int j0 = jbeg + w; j0 < jend; j0 += 8) {
    const int j1 = j0 + 4;
    const bool has1 = (j1 < jend);
    const int k0 = j0 * 32;
    const int k1 = has1 ? j1 * 32 : k0;
    f32x16 sa = {}, sb = {};
    const u16* krow0 = Kb + (size_t)(k0 + l31) * ND + h * 8;
    const u16* krow1 = Kb + (size_t)(k1 + l31) * ND + h * 8;
#pragma unroll
    for (int sI = 0; sI < 8; ++sI) {
      sa = mfma32(ldb(krow0 + sI * 16), qf[sI], sa);
      sb = mfma32(ldb(krow1 + sI * 16), qf[sI], sb);
    }
    // sa[r2] = S^T[key=(r2&3)+8*(r2>>2)+4h][q=l31]
    if (j0 == qt) {
#pragma unroll
      for (int r2 = 0; r2 < 16; ++r2) {
        const int kk = (r2 & 3) + 8 * (r2 >> 2) + 4 * h;
        if (kk > l31) sa[r2] = -1e30f;
      }
    }
    if (has1) {
      if (j1 == qt) {
#pragma unroll
        for (int r2 = 0; r2 < 16; ++r2) {
          const int kk = (r2 & 3) + 8 * (r2 >> 2) + 4 * h;
          if (kk > l31) sb[r2] = -1e30f;
        }
      }
    } else {
#pragma unroll
      for (int r2 = 0; r2 < 16; ++r2) sb[r2] = -1e30f;
    }
    float mt = sa[0];
#pragma unroll
    for (int r2 = 1; r2 < 16; ++r2) mt = fmaxf(mt, sa[r2]);
#pragma unroll
    for (int r2 = 0; r2 < 16; ++r2) mt = fmaxf(mt, sb[r2]);
    mt = fmaxf(mt, __shfl_xor(mt, 32));
    if (__any(mt > m_run + 8.f)) {        // defer-max (T13)
      const float mn = fmaxf(m_run, mt);
      const float f = __builtin_amdgcn_exp2f(m_run - mn);
      l_run *= f;
#pragma unroll
      for (int d0 = 0; d0 < 4; ++d0) ot[d0] *= f;
      m_run = mn;
    }
    float ps = 0.f;
#pragma unroll
    for (int r2 = 0; r2 < 16; ++r2) {
      sa[r2] = __builtin_amdgcn_exp2f(sa[r2] - m_run);
      ps += sa[r2];
    }
#pragma unroll
    for (int r2 = 0; r2 < 16; ++r2) {
      sb[r2] = __builtin_amdgcn_exp2f(sb[r2] - m_run);
      ps += sb[r2];
    }
    ps += __shfl_xor(ps, 32);
    l_run += ps;
    bf16x8 pf0a, pf0b, pf1a, pf1b;
    pack_pf(sa, pf0a, pf0b);
    pack_pf(sb, pf1a, pf1b);
#pragma unroll
    for (int d0 = 0; d0 < 4; ++d0) {
      const u16* vrow0 = VTb + (size_t)(d0 * 32 + l31) * NT + k0 + h * 8;
      const u16* vrow1 = VTb + (size_t)(d0 * 32 + l31) * NT + k1 + h * 8;
      ot[d0] = mfma32(ldb(vrow0), pf0a, ot[d0]);        // O^T[d][q]
      ot[d0] = mfma32(ldb(vrow0 + 16), pf0b, ot[d0]);
      ot[d0] = mfma32(ldb(vrow1), pf1a, ot[d0]);
      ot[d0] = mfma32(ldb(vrow1 + 16), pf1b, ot[d0]);
    }
  }

  // ---- cross-wave combine (unnormalized) ----
  if (h == 0) { smem_m[w][l31] = m_run; smem_l[w][l31] = l_run; }
  __syncthreads();
  float mstar = smem_m[0][l31];
#pragma unroll
  for (int wv = 1; wv < 4; ++wv) mstar = fmaxf(mstar, smem_m[wv][l31]);
  float lstar = 0.f;
#pragma unroll
  for (int wv = 0; wv < 4; ++wv)
    lstar += smem_l[wv][l31] * __builtin_amdgcn_exp2f(smem_m[wv][l31] - mstar);
  const float fw = __builtin_amdgcn_exp2f(m_run - mstar);
  for (int rnd = 0; rnd < 4; ++rnd) {
    if (w == rnd) {
#pragma unroll
      for (int d0 = 0; d0 < 4; ++d0)
#pragma unroll
        for (int r2 = 0; r2 < 16; ++r2) {
          const int d = d0 * 32 + (r2 & 3) + 8 * (r2 >> 2) + 4 * h;
          const float v = ot[d0][r2] * fw;
          if (rnd == 0) smemO[d][l31] = v;
          else smemO[d][l31] += v;
        }
    }
    __syncthreads();
  }
  const int slot = ((b * 128 + qt) << 2) + c;
  if (tid < 32) {
    ml[(size_t)slot * 64 + tid] = mstar;
    ml[(size_t)slot * 64 + 32 + tid] = lstar;
  }
  {
    const int q = tid >> 3;
    const int dbase = (tid & 7) * 16;
    u32x4 o0, o1;
#pragma unroll
    for (int k = 0; k < 4; ++k)
      o0[k] = cvt_pk_bf16(smemO[dbase + 2 * k][q], smemO[dbase + 2 * k + 1][q]);
#pragma unroll
    for (int k = 0; k < 4; ++k)
      o1[k] = cvt_pk_bf16(smemO[dbase + 8 + 2 * k][q], smemO[dbase + 9 + 2 * k][q]);
    u16* dst = opart + (size_t)slot * 4096 + q * ND + dbase;
    *reinterpret_cast<u32x4*>(dst) = o0;
    *reinterpret_cast<u32x4*>(dst + 8) = o1;
  }
}

// ---------------- Kernel 3: split-K combine --------------------------------
// 512 blocks (b, qt) XCD-affine with the writer's mapping -> partials L2-hot.
__global__ __launch_bounds__(256, 4) void ah_comb(
    const u16* __restrict__ opart, const float* __restrict__ ml,
    float* __restrict__ out) {
  const int bid = blockIdx.x;
  const int x = bid & 7;
  const int r = bid >> 3;                 // 0..63
  const int b = x >> 1;
  const int p = x & 1;
  const int qt = (126 + p) - 2 * r;
  const int q0 = qt * 32;
  const int nch = (qt + 32) >> 5;
  const int slot0 = (b * 128 + qt) << 2;

  const int tid = threadIdx.x;
  const int q = tid >> 3;
  const int dbase = (tid & 7) * 16;

  float mi0 = -1e30f, mi1 = -1e30f, mi2 = -1e30f, mi3 = -1e30f;
  mi0 = ml[(size_t)slot0 * 64 + q];
  if (nch > 1) mi1 = ml[(size_t)(slot0 + 1) * 64 + q];
  if (nch > 2) mi2 = ml[(size_t)(slot0 + 2) * 64 + q];
  if (nch > 3) mi3 = ml[(size_t)(slot0 + 3) * 64 + q];
  const float M = fmaxf(fmaxf(mi0, mi1), fmaxf(mi2, mi3));
  float sc0 = __builtin_amdgcn_exp2f(mi0 - M);
  float sc1 = __builtin_amdgcn_exp2f(mi1 - M);
  float sc2 = __builtin_amdgcn_exp2f(mi2 - M);
  float sc3 = __builtin_amdgcn_exp2f(mi3 - M);
  float L = ml[(size_t)slot0 * 64 + 32 + q] * sc0;
  if (nch > 1) L += ml[(size_t)(slot0 + 1) * 64 + 32 + q] * sc1;
  if (nch > 2) L += ml[(size_t)(slot0 + 2) * 64 + 32 + q] * sc2;
  if (nch > 3) L += ml[(size_t)(slot0 + 3) * 64 + 32 + q] * sc3;

  float acc[16];
#pragma unroll
  for (int k = 0; k < 16; ++k) acc[k] = 0.f;
#pragma unroll
  for (int i = 0; i < 4; ++i) {
    if (i < nch) {
      const float sc = (i == 0) ? sc0 : (i == 1) ? sc1 : (i == 2) ? sc2 : sc3;
      const u16* src = opart + (size_t)(slot0 + i) * 4096 + q * ND + dbase;
      u32x4 w0 = *reinterpret_cast<const u32x4*>(src);
      u32x4 w1 = *reinterpret_cast<const u32x4*>(src + 8);
#pragma unroll
      for (int k = 0; k < 4; ++k) {
        acc[2 * k] += sc * __uint_as_float(w0[k] << 16);
        acc[2 * k + 1] += sc * __uint_as_float(w0[k] & 0xffff0000u);
        acc[8 + 2 * k] += sc * __uint_as_float(w1[k] << 16);
        acc[9 + 2 * k] += sc * __uint_as_float(w1[k] & 0xffff0000u);
      }
    }
  }
  const float linv = 1.0f / L;
  float* orow = out + (size_t)b * NT * ND + (size_t)(q0 + q) * ND + dbase;
#pragma unroll
  for (int cc = 0; cc < 4; ++cc) {
    f32x4 v4;
#pragma unroll
    for (int e = 0; e < 4; ++e) v4[e] = acc[cc * 4 + e] * linv;
    *reinterpret_cast<f32x4*>(orow + cc * 4) = v4;
  }
}

extern "C" void kernel_launch(void* const* d_in, const int* in_sizes, int n_in,
                              void* d_out, int out_size, void* d_ws, size_t ws_size,
                              hipStream_t stream) {
  const float* X = (const float*)d_in[0];
  const float* Wq = (const float*)d_in[1];
  const float* Wk = (const float*)d_in[2];
  const float* Wv = (const float*)d_in[3];
  u16* ws = (u16*)d_ws;
  u16* wt = ws;                            // 393216 u16
  u16* qb = wt + 393216;                   // 2097152 u16
  u16* kb = qb + 2097152;                  // 2097152 u16
  u16* vtb = kb + 2097152;                 // 2097152 u16
  u16* opart = vtb + 2097152;              // 2048*4096 u16 = 8388608
  float* ml = (float*)(opart + 8388608);   // 2048*64 f32 (byte off 30146560)
  float* out = (float*)d_out;

  ah_prep<<<96, 256, 0, stream>>>(Wq, Wk, Wv, wt);
  ah_proj<<<512, 256, 0, stream>>>(X, wt, qb, kb, vtb);
  ah_attn_sk<<<1280, 256, 0, stream>>>(qb, kb, vtb, opart, ml);
  ah_comb<<<512, 256, 0, stream>>>(opart, ml, out);
}

// Round 5
// 311.720 us; speedup vs baseline: 1.0008x; 1.0008x over previous
//
#include <hip/hip_runtime.h>
#include <hip/hip_bf16.h>

// Problem constants
#define NB 4
#define NT 4096
#define NE 1024
#define ND 128
// log2(e) / sqrt(128): folded into Wq at prep so attention uses exp2 directly.
#define QSCALE 0.12751741f

typedef unsigned u32x4 __attribute__((ext_vector_type(4)));
typedef float f32x4 __attribute__((ext_vector_type(4)));
typedef float f32x16 __attribute__((ext_vector_type(16)));
typedef __bf16 bf16x8 __attribute__((ext_vector_type(8)));
typedef unsigned short u16;

__device__ __forceinline__ unsigned cvt_pk_bf16(float lo, float hi) {
  unsigned r;
  asm("v_cvt_pk_bf16_f32 %0, %1, %2" : "=v"(r) : "v"(lo), "v"(hi));
  return r;
}
__device__ __forceinline__ void permswap(unsigned& a, unsigned& b) {
  asm("v_permlane32_swap_b32 %0, %1" : "+v"(a), "+v"(b));
}
__device__ __forceinline__ u16 f2bf(float f) {  // RNE f32->bf16
  unsigned x = __float_as_uint(f);
  x += 0x7fffu + ((x >> 16) & 1u);
  return (u16)(x >> 16);
}
__device__ __forceinline__ f32x16 mfma32(bf16x8 a, bf16x8 b, f32x16 c) {
  return __builtin_amdgcn_mfma_f32_32x32x16_bf16(a, b, c, 0, 0, 0);
}
__device__ __forceinline__ bf16x8 ldb(const u16* p) {
  return *reinterpret_cast<const bf16x8*>(p);
}
// P(f32x16, C/D layout) -> two bf16x8 B-fragments for PV
__device__ __forceinline__ void pack_pf(const f32x16& pr, bf16x8& f0, bf16x8& f1) {
  unsigned pk[8];
#pragma unroll
  for (int i = 0; i < 8; ++i) pk[i] = cvt_pk_bf16(pr[2 * i], pr[2 * i + 1]);
  permswap(pk[0], pk[2]);
  permswap(pk[1], pk[3]);
  permswap(pk[4], pk[6]);
  permswap(pk[5], pk[7]);
  u32x4 t0, t1;
  t0[0] = pk[0]; t0[1] = pk[1]; t0[2] = pk[2]; t0[3] = pk[3];
  t1[0] = pk[4]; t1[1] = pk[5]; t1[2] = pk[6]; t1[3] = pk[7];
  f0 = __builtin_bit_cast(bf16x8, t0);
  f1 = __builtin_bit_cast(bf16x8, t1);
}

// ---------------- Kernel 0: W[e][d] -> WT bf16 [3][128 d][1024 e] ----------
__global__ void ah_prep(const float* __restrict__ Wq, const float* __restrict__ Wk,
                        const float* __restrict__ Wv, u16* __restrict__ wt) {
  const int m = blockIdx.x >> 5;
  const int r = blockIdx.x & 31;
  const int e0 = (r >> 1) * 64;
  const int d0 = (r & 1) * 64;
  const float* W = (m == 0) ? Wq : (m == 1) ? Wk : Wv;
  const float s = (m == 0) ? QSCALE : 1.0f;
  __shared__ u16 lds[64][68];             // [d][e]
  const int t = threadIdx.x;
  const int row = t >> 2;
  const int c0 = (t & 3) * 16;
  const float* src = W + (size_t)(e0 + row) * ND + d0 + c0;
#pragma unroll
  for (int i = 0; i < 16; i += 4) {
    f32x4 v = *reinterpret_cast<const f32x4*>(src + i);
#pragma unroll
    for (int j = 0; j < 4; ++j) lds[c0 + i + j][row] = f2bf(v[j] * s);
  }
  __syncthreads();
  const int d = t >> 2;
  const int ec = (t & 3) * 16;
  u16* dst = wt + (size_t)m * NE * ND + (size_t)(d0 + d) * NE + e0 + ec;
  u32x4 o0, o1;
#pragma unroll
  for (int j = 0; j < 4; ++j)
    o0[j] = (unsigned)lds[d][ec + 2 * j] | ((unsigned)lds[d][ec + 2 * j + 1] << 16);
#pragma unroll
  for (int j = 0; j < 4; ++j)
    o1[j] = (unsigned)lds[d][ec + 8 + 2 * j] | ((unsigned)lds[d][ec + 8 + 2 * j + 1] << 16);
  *reinterpret_cast<u32x4*>(dst) = o0;
  *reinterpret_cast<u32x4*>(dst + 8) = o1;
}

// ---------------- Kernel 1: QKV projection, mat-split ----------------------
// 1536 blocks = 8 XCDs x (64 row-tiles x 3 mats). XCD x owns row-tiles
// [64x, 64x+64); the 3 mats of one row-tile are consecutive bids on the SAME
// XCD -> X rows L2-hot across mats. 4 waves/block; wave w = d-cols [32w,32w+32).
__global__ __launch_bounds__(256, 2) void ah_proj(
    const float* __restrict__ X, const u16* __restrict__ wt,
    u16* __restrict__ qb, u16* __restrict__ kb, u16* __restrict__ vtb) {
  const int x = blockIdx.x & 7;
  const int s = blockIdx.x >> 3;          // 0..191
  const int rtl = s / 3;                  // 0..63
  const int mat = s - 3 * rtl;
  const int row0 = (x * 64 + rtl) * 32;
  const int tid = threadIdx.x;
  const int w = tid >> 6;
  const int lane = tid & 63;
  const int l31 = lane & 31;
  const int h = lane >> 5;

  const float* xrow = X + (size_t)(row0 + l31) * NE + h * 8;
  const u16* wp = wt + (size_t)mat * NE * ND + (size_t)(w * 32 + l31) * NE + h * 8;

  f32x16 acc = {};

  if (mat < 2) {
#pragma unroll 4
    for (int e0 = 0; e0 < NE; e0 += 16) {
      f32x4 x0 = *reinterpret_cast<const f32x4*>(xrow + e0);
      f32x4 x1 = *reinterpret_cast<const f32x4*>(xrow + e0 + 4);
      u32x4 xw;
      xw[0] = cvt_pk_bf16(x0[0], x0[1]);
      xw[1] = cvt_pk_bf16(x0[2], x0[3]);
      xw[2] = cvt_pk_bf16(x1[0], x1[1]);
      xw[3] = cvt_pk_bf16(x1[2], x1[3]);
      bf16x8 xf = __builtin_bit_cast(bf16x8, xw);
      acc = mfma32(xf, ldb(wp + e0), acc);      // D[t][d]
    }
    u16* dst = (mat == 0) ? qb : kb;
    const int col = w * 32 + l31;
#pragma unroll
    for (int r = 0; r < 16; ++r) {
      const int trow = row0 + (r & 3) + 8 * (r >> 2) + 4 * h;
      dst[(size_t)trow * ND + col] = f2bf(acc[r]);
    }
  } else {
#pragma unroll 4
    for (int e0 = 0; e0 < NE; e0 += 16) {
      f32x4 x0 = *reinterpret_cast<const f32x4*>(xrow + e0);
      f32x4 x1 = *reinterpret_cast<const f32x4*>(xrow + e0 + 4);
      u32x4 xw;
      xw[0] = cvt_pk_bf16(x0[0], x0[1]);
      xw[1] = cvt_pk_bf16(x0[2], x0[3]);
      xw[2] = cvt_pk_bf16(x1[0], x1[1]);
      xw[3] = cvt_pk_bf16(x1[2], x1[3]);
      bf16x8 xf = __builtin_bit_cast(bf16x8, xw);
      acc = mfma32(ldb(wp + e0), xf, acc);      // D[d][t]  (V^T)
    }
    const int bb = row0 >> 12;
    const int tt = (row0 & 4095) + l31;
#pragma unroll
    for (int r = 0; r < 16; ++r) {
      const int d = w * 32 + (r & 3) + 8 * (r >> 2) + 4 * h;
      vtb[(size_t)bb * ND * NT + (size_t)d * NT + tt] = f2bf(acc[r]);
    }
  }
}

// ---------------- Kernel 2: causal flash attention, partial split-K --------
// 768 blocks x 4 waves. Per batch: 192 units; qt>=64 split into 2 chunks
// (sizes 32..64 tiles), qt<64 whole (1..64 tiles) -> balanced, work-descending.
// XCD-affine: xcd = 2b+half. Unsplit units normalize & write f32 out directly;
// split units write unnormalized partials (merged by ah_comb).
__global__ __launch_bounds__(256, 2) void ah_attn(
    const u16* __restrict__ qg, const u16* __restrict__ kg,
    const u16* __restrict__ vtg, u16* __restrict__ opart,
    float* __restrict__ ml, float* __restrict__ out) {
  __shared__ float smem_m[4][32];
  __shared__ float smem_l[4][32];
  __shared__ float smem_linv[32];
  __shared__ float smemO[128][33];

  const int bid = blockIdx.x;
  const int x = bid & 7;
  const int sh = bid >> 3;                // 0..95
  const int b = x >> 1;
  const int s = sh * 2 + (x & 1);         // 0..191, ~work-descending
  int qt, c, jbeg, jend, split;
  {
    const int q3 = s / 3;
    const int rem = s - 3 * q3;
    if (rem < 2) {                        // A: qt in [64,127], 2 chunks
      const int i = q3 * 2 + rem;         // 0..127
      qt = 127 - (i >> 1);
      c = i & 1;
      const int n0 = (qt + 2) >> 1;
      split = 1;
      jbeg = c ? n0 : 0;
      jend = c ? (qt + 1) : n0;
    } else {                              // B: qt in [0,63], whole
      qt = 63 - q3;
      c = 0;
      split = 0;
      jbeg = 0;
      jend = qt + 1;
    }
  }
  const int q0 = qt * 32;

  const int tid = threadIdx.x;
  const int w = tid >> 6;
  const int lane = tid & 63;
  const int l31 = lane & 31;
  const int h = lane >> 5;

  const u16* Qb = qg + (size_t)b * NT * ND;
  const u16* Kb = kg + (size_t)b * NT * ND;
  const u16* VTb = vtg + (size_t)b * ND * NT;

  bf16x8 qf[8];
  {
    const u16* qrow = Qb + (size_t)(q0 + l31) * ND + h * 8;
#pragma unroll
    for (int sI = 0; sI < 8; ++sI) qf[sI] = ldb(qrow + sI * 16);
  }

  float m_run = -1e30f, l_run = 0.f;
  f32x16 ot[4] = {};

  for (int j0 = jbeg + w; j0 < jend; j0 += 8) {
    const int j1 = j0 + 4;
    const bool has1 = (j1 < jend);
    const int k0 = j0 * 32;
    const int k1 = has1 ? j1 * 32 : k0;
    f32x16 sa = {}, sb = {};
    const u16* krow0 = Kb + (size_t)(k0 + l31) * ND + h * 8;
    const u16* krow1 = Kb + (size_t)(k1 + l31) * ND + h * 8;
#pragma unroll
    for (int sI = 0; sI < 8; ++sI) {
      sa = mfma32(ldb(krow0 + sI * 16), qf[sI], sa);
      sb = mfma32(ldb(krow1 + sI * 16), qf[sI], sb);
    }
    // sa[r2] = S^T[key=(r2&3)+8*(r2>>2)+4h][q=l31]
    if (j0 == qt) {
#pragma unroll
      for (int r2 = 0; r2 < 16; ++r2) {
        const int kk = (r2 & 3) + 8 * (r2 >> 2) + 4 * h;
        if (kk > l31) sa[r2] = -1e30f;
      }
    }
    if (has1) {
      if (j1 == qt) {
#pragma unroll
        for (int r2 = 0; r2 < 16; ++r2) {
          const int kk = (r2 & 3) + 8 * (r2 >> 2) + 4 * h;
          if (kk > l31) sb[r2] = -1e30f;
        }
      }
    } else {
#pragma unroll
      for (int r2 = 0; r2 < 16; ++r2) sb[r2] = -1e30f;
    }
    float mt = sa[0];
#pragma unroll
    for (int r2 = 1; r2 < 16; ++r2) mt = fmaxf(mt, sa[r2]);
#pragma unroll
    for (int r2 = 0; r2 < 16; ++r2) mt = fmaxf(mt, sb[r2]);
    mt = fmaxf(mt, __shfl_xor(mt, 32));
    if (__any(mt > m_run + 8.f)) {        // defer-max (T13)
      const float mn = fmaxf(m_run, mt);
      const float f = __builtin_amdgcn_exp2f(m_run - mn);
      l_run *= f;
#pragma unroll
      for (int d0 = 0; d0 < 4; ++d0) ot[d0] *= f;
      m_run = mn;
    }
    float ps = 0.f;
#pragma unroll
    for (int r2 = 0; r2 < 16; ++r2) {
      sa[r2] = __builtin_amdgcn_exp2f(sa[r2] - m_run);
      ps += sa[r2];
    }
#pragma unroll
    for (int r2 = 0; r2 < 16; ++r2) {
      sb[r2] = __builtin_amdgcn_exp2f(sb[r2] - m_run);
      ps += sb[r2];
    }
    ps += __shfl_xor(ps, 32);
    l_run += ps;
    bf16x8 pf0a, pf0b, pf1a, pf1b;
    pack_pf(sa, pf0a, pf0b);
    pack_pf(sb, pf1a, pf1b);
#pragma unroll
    for (int d0 = 0; d0 < 4; ++d0) {
      const u16* vrow0 = VTb + (size_t)(d0 * 32 + l31) * NT + k0 + h * 8;
      const u16* vrow1 = VTb + (size_t)(d0 * 32 + l31) * NT + k1 + h * 8;
      ot[d0] = mfma32(ldb(vrow0), pf0a, ot[d0]);        // O^T[d][q]
      ot[d0] = mfma32(ldb(vrow0 + 16), pf0b, ot[d0]);
      ot[d0] = mfma32(ldb(vrow1), pf1a, ot[d0]);
      ot[d0] = mfma32(ldb(vrow1 + 16), pf1b, ot[d0]);
    }
  }

  // ---- cross-wave combine ----
  if (h == 0) { smem_m[w][l31] = m_run; smem_l[w][l31] = l_run; }
  __syncthreads();
  float mstar = smem_m[0][l31];
#pragma unroll
  for (int wv = 1; wv < 4; ++wv) mstar = fmaxf(mstar, smem_m[wv][l31]);
  float lstar = 0.f;
#pragma unroll
  for (int wv = 0; wv < 4; ++wv)
    lstar += smem_l[wv][l31] * __builtin_amdgcn_exp2f(smem_m[wv][l31] - mstar);
  if (!split && tid < 32) smem_linv[tid] = 1.0f / lstar;
  const float fw = __builtin_amdgcn_exp2f(m_run - mstar);
  for (int rnd = 0; rnd < 4; ++rnd) {
    if (w == rnd) {
#pragma unroll
      for (int d0 = 0; d0 < 4; ++d0)
#pragma unroll
        for (int r2 = 0; r2 < 16; ++r2) {
          const int d = d0 * 32 + (r2 & 3) + 8 * (r2 >> 2) + 4 * h;
          const float v = ot[d0][r2] * fw;
          if (rnd == 0) smemO[d][l31] = v;
          else smemO[d][l31] += v;
        }
    }
    __syncthreads();
  }
  const int q = tid >> 3;
  const int dbase = (tid & 7) * 16;
  if (!split) {
    const float linv = smem_linv[q];
    float* orow = out + (size_t)b * NT * ND + (size_t)(q0 + q) * ND + dbase;
#pragma unroll
    for (int cc = 0; cc < 4; ++cc) {
      f32x4 v4;
#pragma unroll
      for (int e = 0; e < 4; ++e) v4[e] = smemO[dbase + cc * 4 + e][q] * linv;
      *reinterpret_cast<f32x4*>(orow + cc * 4) = v4;
    }
  } else {
    const int slot = ((b << 6) + (qt - 64)) * 2 + c;
    if (tid < 32) {
      ml[(size_t)slot * 64 + tid] = mstar;
      ml[(size_t)slot * 64 + 32 + tid] = lstar;
    }
    u32x4 o0, o1;
#pragma unroll
    for (int k = 0; k < 4; ++k)
      o0[k] = cvt_pk_bf16(smemO[dbase + 2 * k][q], smemO[dbase + 2 * k + 1][q]);
#pragma unroll
    for (int k = 0; k < 4; ++k)
      o1[k] = cvt_pk_bf16(smemO[dbase + 8 + 2 * k][q], smemO[dbase + 9 + 2 * k][q]);
    u16* dst = opart + (size_t)slot * 4096 + q * ND + dbase;
    *reinterpret_cast<u32x4*>(dst) = o0;
    *reinterpret_cast<u32x4*>(dst + 8) = o1;
  }
}

// ---------------- Kernel 3: 2-chunk combine (qt >= 64 only) ----------------
__global__ __launch_bounds__(256, 4) void ah_comb(
    const u16* __restrict__ opart, const float* __restrict__ ml,
    float* __restrict__ out) {
  const int bid = blockIdx.x;             // 256 = 4 b x 64 qt
  const int b = bid >> 6;
  const int qt = 64 + (bid & 63);
  const int q0 = qt * 32;
  const int slot0 = ((b << 6) + (qt - 64)) * 2;

  const int tid = threadIdx.x;
  const int q = tid >> 3;
  const int dbase = (tid & 7) * 16;

  const float m0 = ml[(size_t)slot0 * 64 + q];
  const float m1 = ml[(size_t)(slot0 + 1) * 64 + q];
  const float M = fmaxf(m0, m1);
  const float sc0 = __builtin_amdgcn_exp2f(m0 - M);
  const float sc1 = __builtin_amdgcn_exp2f(m1 - M);
  const float L = ml[(size_t)slot0 * 64 + 32 + q] * sc0 +
                  ml[(size_t)(slot0 + 1) * 64 + 32 + q] * sc1;
  const float linv = 1.0f / L;

  const u16* s0 = opart + (size_t)slot0 * 4096 + q * ND + dbase;
  const u16* s1 = s0 + 4096;
  u32x4 a0 = *reinterpret_cast<const u32x4*>(s0);
  u32x4 a1 = *reinterpret_cast<const u32x4*>(s0 + 8);
  u32x4 b0 = *reinterpret_cast<const u32x4*>(s1);
  u32x4 b1 = *reinterpret_cast<const u32x4*>(s1 + 8);
  float acc[16];
#pragma unroll
  for (int k = 0; k < 4; ++k) {
    acc[2 * k]     = sc0 * __uint_as_float(a0[k] << 16) + sc1 * __uint_as_float(b0[k] << 16);
    acc[2 * k + 1] = sc0 * __uint_as_float(a0[k] & 0xffff0000u) + sc1 * __uint_as_float(b0[k] & 0xffff0000u);
    acc[8 + 2 * k] = sc0 * __uint_as_float(a1[k] << 16) + sc1 * __uint_as_float(b1[k] << 16);
    acc[9 + 2 * k] = sc0 * __uint_as_float(a1[k] & 0xffff0000u) + sc1 * __uint_as_float(b1[k] & 0xffff0000u);
  }
  float* orow = out + (size_t)b * NT * ND + (size_t)(q0 + q) * ND + dbase;
#pragma unroll
  for (int cc = 0; cc < 4; ++cc) {
    f32x4 v4;
#pragma unroll
    for (int e = 0; e < 4; ++e) v4[e] = acc[cc * 4 + e] * linv;
    *reinterpret_cast<f32x4*>(orow + cc * 4) = v4;
  }
}

extern "C" void kernel_launch(void* const* d_in, const int* in_sizes, int n_in,
                              void* d_out, int out_size, void* d_ws, size_t ws_size,
                              hipStream_t stream) {
  const float* X = (const float*)d_in[0];
  const float* Wq = (const float*)d_in[1];
  const float* Wk = (const float*)d_in[2];
  const float* Wv = (const float*)d_in[3];
  u16* ws = (u16*)d_ws;
  u16* wt = ws;                            // 393216 u16
  u16* qb = wt + 393216;                   // 2097152 u16
  u16* kb = qb + 2097152;
  u16* vtb = kb + 2097152;
  u16* opart = vtb + 2097152;              // 512 slots x 4096 u16 = 2097152
  float* ml = (float*)(opart + 2097152);   // 512 x 64 f32
  float* out = (float*)d_out;

  ah_prep<<<96, 256, 0, stream>>>(Wq, Wk, Wv, wt);
  ah_proj<<<1536, 256, 0, stream>>>(X, wt, qb, kb, vtb);
  ah_attn<<<768, 256, 0, stream>>>(qb, kb, vtb, opart, ml, out);
  ah_comb<<<256, 256, 0, stream>>>(opart, ml, out);
}